// Round 4
// baseline (160.275 us; speedup 1.0000x reference)
//
#include <hip/hip_runtime.h>
#include <hip/hip_bf16.h>
#include <stdint.h>

typedef __attribute__((ext_vector_type(8))) __bf16 bf16x8;
typedef __attribute__((ext_vector_type(4))) float f32x4;
typedef __attribute__((ext_vector_type(4))) int   i32x4;
typedef __attribute__((ext_vector_type(4))) uint32_t u32x4;

#define B_SZ 8
#define E_SZ 8192
#define T_SZ 2048
#define D_SZ 256
#define H_SZ 256
#define NP   768      // interleaved i,g,o columns

#define BM 128
#define BN 96
#define NTHR 512
#define NWG  4096     // (65536/BM) * (768/BN) = 512 * 8
#define BLDS (BN * D_SZ * 2)   // 49152 B

#define NODE_H_OFF 0
#define NODE_C_OFF (B_SZ*T_SZ*H_SZ)                       // 4194304
#define EDGE_H_OFF (2*B_SZ*T_SZ*H_SZ)                     // 8388608
#define EDGE_C_OFF (2*B_SZ*T_SZ*H_SZ + B_SZ*E_SZ*H_SZ)    // 25165824

__device__ __forceinline__ uint32_t pk_bf16(float a, float b) {
    uint32_t ua = __float_as_uint(a);
    uint32_t ub = __float_as_uint(b);
    ua += 0x7fffu + ((ua >> 16) & 1u);   // RNE
    ub += 0x7fffu + ((ub >> 16) & 1u);
    return (ua >> 16) | (ub & 0xffff0000u);
}

// weight_ih [256][1024] f32 -> Wt [768][256] bf16 (transposed, gate-interleaved:
// n' = 48*t + 16*s + u  <->  original col gate_off(s) + 16*t + u, s in {i,g,o})
// f-gate columns dropped (c0 == 0). bias similarly permuted into biasp[768].
__global__ void wcvt_kernel(const float* __restrict__ W, const float* __restrict__ bias,
                            uint16_t* __restrict__ Wt, float* __restrict__ biasp) {
    int id = blockIdx.x * 256 + threadIdx.x;
    if (id < 256 * 768) {
        int k = id / 768;
        int q = id - k * 768;                 // q in [0,768): 0-255 i, 256-511 g, 512-767 o
        int col = (q < 256) ? q : (q + 256);  // skip f chunk [256,512)
        int s = q >> 8;
        int j = q & 255;
        int np = 48 * (j >> 4) + 16 * s + (j & 15);
        uint32_t ua = __float_as_uint(W[k * 1024 + col]);
        ua += 0x7fffu + ((ua >> 16) & 1u);
        Wt[np * 256 + k] = (uint16_t)(ua >> 16);
        if (k == 0) biasp[np] = bias[col];
    }
}

// GEMM [65536 x 256] (f32->bf16 in-reg) @ Wt^T [256 x 768] + fused activations.
// Single-stage: B (96 x 256, 48 KB) staged to LDS once (XOR-swizzled), ONE
// barrier; A read direct global->reg per fragment (coalesced 16 rows x 128 B),
// full K=256 accumulated in one pass. 8 waves (4M x 2N), wave tile 32x48.
__launch_bounds__(NTHR, 4)
__global__ void gemm_act_kernel(const float* __restrict__ A,
                                const uint16_t* __restrict__ Wt,
                                const float* __restrict__ biasp,
                                float* __restrict__ out) {
    __shared__ __align__(16) char Bs[BLDS];

    const int tid  = threadIdx.x;
    // XCD-aware bijective swizzle (NWG % 8 == 0): 8 n-blocks of an m-tile
    // are consecutive on the SAME XCD -> A rows L2-shared, B L2-shared.
    const int bid  = blockIdx.x;
    const int wg   = (bid & 7) * (NWG / 8) + (bid >> 3);
    const int mb   = wg >> 3;         // 0..511
    const int nb   = wg & 7;          // 0..7
    const int m0   = mb * BM;
    const int n0   = nb * BN;

    const int wid  = tid >> 6;
    const int lane = tid & 63;
    const int wm   = wid >> 1;        // 0..3  (M split)
    const int wn   = wid & 1;         // 0..1  (N split)
    const int l15  = lane & 15;
    const int lq   = lane >> 4;

    // ---- stage B once: linear LDS dest, inverse-swizzled global source
    #pragma unroll
    for (int r2 = 0; r2 < 6; ++r2) {
        int p    = (r2 * NTHR + tid) * 16;            // linear LDS byte pos
        int row  = p >> 9;                            // 512 B per row
        int cphy = p & 511;
        int clog = cphy ^ ((row & 7) << 4);           // involution
        const uint16_t* g = Wt + (n0 + row) * 256 + (clog >> 1);
        __builtin_amdgcn_global_load_lds(
            (const __attribute__((address_space(1))) uint32_t*)g,
            (__attribute__((address_space(3))) uint32_t*)(Bs + p), 16, 0, 0);
    }

    // A fragment base: rows m0 + wm*32 + {0,16} + l15, k chunk lq*8
    const float* a0base = A + (size_t)(m0 + wm * 32 + l15) * D_SZ + lq * 8;
    const float* a1base = a0base + 16 * D_SZ;

    // preload A for kk=0
    f32x4 xc[2][2];
    xc[0][0] = *(const f32x4*)(a0base);
    xc[0][1] = *(const f32x4*)(a0base + 4);
    xc[1][0] = *(const f32x4*)(a1base);
    xc[1][1] = *(const f32x4*)(a1base + 4);

    __syncthreads();   // B staged (drains A(0) loads too — needed immediately)

    f32x4 acc[2][3];
    #pragma unroll
    for (int mf = 0; mf < 2; ++mf)
        #pragma unroll
        for (int nf = 0; nf < 3; ++nf)
            acc[mf][nf] = (f32x4){0.f, 0.f, 0.f, 0.f};

    const int brow0 = wn * 48 + l15;                  // B rows for nf=0
    #pragma unroll
    for (int kk = 0; kk < 8; ++kk) {
        // prefetch A(kk+1)
        f32x4 xn[2][2];
        if (kk < 7) {
            const float* ga0 = a0base + (kk + 1) * 32;
            const float* ga1 = a1base + (kk + 1) * 32;
            xn[0][0] = *(const f32x4*)(ga0);
            xn[0][1] = *(const f32x4*)(ga0 + 4);
            xn[1][0] = *(const f32x4*)(ga1);
            xn[1][1] = *(const f32x4*)(ga1 + 4);
        }
        // B frags from LDS (swizzled)
        const int kb = kk * 64 + lq * 16;
        bf16x8 bfr[3];
        #pragma unroll
        for (int nf = 0; nf < 3; ++nf) {
            int row = brow0 + nf * 16;
            bfr[nf] = *(const bf16x8*)(Bs + row * 512 + (kb ^ ((row & 7) << 4)));
        }
        // cvt A(kk) f32 -> bf16
        bf16x8 af[2];
        #pragma unroll
        for (int mf = 0; mf < 2; ++mf) {
            u32x4 v = { pk_bf16(xc[mf][0].x, xc[mf][0].y), pk_bf16(xc[mf][0].z, xc[mf][0].w),
                        pk_bf16(xc[mf][1].x, xc[mf][1].y), pk_bf16(xc[mf][1].z, xc[mf][1].w) };
            af[mf] = __builtin_bit_cast(bf16x8, v);
        }
        #pragma unroll
        for (int mf = 0; mf < 2; ++mf)
            #pragma unroll
            for (int nf = 0; nf < 3; ++nf)
                acc[mf][nf] = __builtin_amdgcn_mfma_f32_16x16x32_bf16(
                    af[mf], bfr[nf], acc[mf][nf], 0, 0, 0);
        if (kk < 7) {
            #pragma unroll
            for (int mf = 0; mf < 2; ++mf) {
                xc[mf][0] = xn[mf][0];
                xc[mf][1] = xn[mf][1];
            }
        }
    }

    // --- fused epilogue: c = sig(i)*tanh(g), h = sig(o)*tanh(o) = (1-e^-o)/(1+e^-2o)
    const float L2E = 1.44269504088896340736f;
    const int jg = nb * 2 + wn;                       // j-group 0..15
    const int jj = jg * 16 + l15;                     // hidden index 0..255
    const int bb = n0 + wn * 48 + l15;
    const float bi = biasp[bb];
    const float bg = biasp[bb + 16];
    const float bo = biasp[bb + 32];
    float* __restrict__ eh = out + EDGE_H_OFF;
    float* __restrict__ ec = out + EDGE_C_OFF;
    #pragma unroll
    for (int mf = 0; mf < 2; ++mf) {
        const int mbase = m0 + wm * 32 + mf * 16 + lq * 4;
        #pragma unroll
        for (int r = 0; r < 4; ++r) {
            const size_t m = (size_t)(mbase + r);
            float pi = acc[mf][0][r] + bi;
            float pg = acc[mf][1][r] + bg;
            float po = acc[mf][2][r] + bo;
            float ei = __builtin_amdgcn_exp2f(-L2E * pi);          // e^-i
            float eg = __builtin_amdgcn_exp2f(-2.f * L2E * pg);    // e^-2g
            float eo = __builtin_amdgcn_exp2f(-L2E * po);          // e^-o
            float c  = (1.f - eg) * __builtin_amdgcn_rcpf((1.f + ei) * (1.f + eg));
            float h  = (1.f - eo) * __builtin_amdgcn_rcpf(1.f + eo * eo);
            eh[m * H_SZ + jj] = h;
            ec[m * H_SZ + jj] = c;
        }
    }
}

// node_{h,c}[b,t,:] = mean over k of edge_{h,c}[b, prev[t,k], :]
// one wave per (b,t) pair; float4 per lane covers the 256-wide row.
__global__ void node_mean_kernel(const int* __restrict__ prev,
                                 const float* __restrict__ outr,
                                 float* __restrict__ out) {
    int gid  = blockIdx.x * 4 + (threadIdx.x >> 6);       // 0..16383
    int lane = threadIdx.x & 63;
    int b = gid >> 11;
    int t = gid & 2047;
    const float* eh = outr + EDGE_H_OFF + (size_t)b * E_SZ * H_SZ;
    const float* ec = outr + EDGE_C_OFF + (size_t)b * E_SZ * H_SZ;
    i32x4 e4 = *(const i32x4*)(prev + t * 4);
    f32x4 hs = (f32x4){0.f,0.f,0.f,0.f};
    f32x4 cs = (f32x4){0.f,0.f,0.f,0.f};
    #pragma unroll
    for (int k = 0; k < 4; ++k) {
        size_t off = (size_t)e4[k] * H_SZ + lane * 4;
        hs += *(const f32x4*)(eh + off);
        cs += *(const f32x4*)(ec + off);
    }
    hs *= 0.25f; cs *= 0.25f;
    size_t o = (size_t)(b * T_SZ + t) * H_SZ + lane * 4;
    *(f32x4*)(out + NODE_H_OFF + o) = hs;
    *(f32x4*)(out + NODE_C_OFF + o) = cs;
}

extern "C" void kernel_launch(void* const* d_in, const int* in_sizes, int n_in,
                              void* d_out, int out_size, void* d_ws, size_t ws_size,
                              hipStream_t stream) {
    const float* edge_input = (const float*)d_in[0];
    const float* weight_ih  = (const float*)d_in[1];
    // d_in[2] = weight_hh: mathematically dead (node_h read before write => 0)
    const float* bias       = (const float*)d_in[3];
    const int*   prev_idx   = (const int*)d_in[4];
    float* out = (float*)d_out;

    uint16_t* Wt    = (uint16_t*)d_ws;                    // 768*256*2 = 384 KiB
    float*    biasp = (float*)((char*)d_ws + NP * 256 * 2);

    wcvt_kernel<<<(256 * 768 + 255) / 256, 256, 0, stream>>>(weight_ih, bias, Wt, biasp);
    gemm_act_kernel<<<NWG, NTHR, 0, stream>>>(edge_input, Wt, biasp, out);
    node_mean_kernel<<<(B_SZ * T_SZ) / 4, 256, 0, stream>>>(prev_idx, out, out);
}

// Round 5
// 89.240 us; speedup vs baseline: 1.7960x; 1.7960x over previous
//
#include <hip/hip_runtime.h>
#include <hip/hip_bf16.h>
#include <stdint.h>

typedef __attribute__((ext_vector_type(8))) __bf16 bf16x8;
typedef __attribute__((ext_vector_type(4))) float f32x4;
typedef __attribute__((ext_vector_type(4))) int   i32x4;
typedef __attribute__((ext_vector_type(4))) uint32_t u32x4;

#define B_SZ 8
#define E_SZ 8192
#define T_SZ 2048
#define D_SZ 256
#define H_SZ 256
#define NP   768      // interleaved i,g,o columns

#define BM 128
#define BN 96
#define BK 64
#define KT 4          // K tiles (256/64)
#define NTHR 512
#define NWG  4096     // (65536/BM) * (768/BN) = 512 * 8

#define BTILE (BN * BK * 2)      // 12288 B per B k-tile
#define BLDS  (KT * BTILE)       // 49152 B
#define ALDS  (BM * BK * 2)      // 16384 B per A buffer

#define NODE_H_OFF 0
#define NODE_C_OFF (B_SZ*T_SZ*H_SZ)                       // 4194304
#define EDGE_H_OFF (2*B_SZ*T_SZ*H_SZ)                     // 8388608
#define EDGE_C_OFF (2*B_SZ*T_SZ*H_SZ + B_SZ*E_SZ*H_SZ)    // 25165824

__device__ __forceinline__ uint32_t pk_bf16(float a, float b) {
    uint32_t ua = __float_as_uint(a);
    uint32_t ub = __float_as_uint(b);
    ua += 0x7fffu + ((ua >> 16) & 1u);   // RNE
    ub += 0x7fffu + ((ub >> 16) & 1u);
    return (ua >> 16) | (ub & 0xffff0000u);
}

// weight_ih [256][1024] f32 -> Wt [768][256] bf16 (transposed, gate-interleaved:
// n' = 48*t + 16*s + u  <->  original col gate_off(s) + 16*t + u, s in {i,g,o})
// f-gate columns dropped (c0 == 0). bias similarly permuted into biasp[768].
__global__ void wcvt_kernel(const float* __restrict__ W, const float* __restrict__ bias,
                            uint16_t* __restrict__ Wt, float* __restrict__ biasp) {
    int id = blockIdx.x * 256 + threadIdx.x;
    if (id < 256 * 768) {
        int k = id / 768;
        int q = id - k * 768;                 // q in [0,768): 0-255 i, 256-511 g, 512-767 o
        int col = (q < 256) ? q : (q + 256);  // skip f chunk [256,512)
        int s = q >> 8;
        int j = q & 255;
        int np = 48 * (j >> 4) + 16 * s + (j & 15);
        uint32_t ua = __float_as_uint(W[k * 1024 + col]);
        ua += 0x7fffu + ((ua >> 16) & 1u);
        Wt[np * 256 + k] = (uint16_t)(ua >> 16);
        if (k == 0) biasp[np] = bias[col];
    }
}

// GEMM [65536 x 256] (f32->bf16 in-reg) @ Wt^T [256 x 768] + fused activations.
// B panel (96x256, 48 KB) staged ONCE via global_load_lds (tile-blocked
// [4][96][128B], XOR-swizzled rows). k-loop stages only A (reg->LDS bf16,
// double-buffered): issue A(t+1) -> MFMA(t) -> pack/write(t+1) -> lgkm-only
// barrier. No vmcnt drain inside the loop (only private reg loads in flight).
__launch_bounds__(NTHR, 4)
__global__ void gemm_act_kernel(const float* __restrict__ A,
                                const uint16_t* __restrict__ Wt,
                                const float* __restrict__ biasp,
                                float* __restrict__ out) {
    __shared__ __align__(16) char Bs[BLDS];
    __shared__ __align__(16) char As[2][ALDS];

    const int tid  = threadIdx.x;
    // XCD-aware bijective swizzle (NWG % 8 == 0): the 8 n-blocks of an m-tile
    // run consecutively on the SAME XCD -> A rows L2-shared across them.
    const int bid  = blockIdx.x;
    const int wg   = (bid & 7) * (NWG / 8) + (bid >> 3);
    const int mb   = wg >> 3;         // 0..511
    const int nb   = wg & 7;          // 0..7
    const int m0   = mb * BM;
    const int n0   = nb * BN;

    const int wid  = tid >> 6;
    const int lane = tid & 63;
    const int wm   = wid >> 1;        // 0..3  (M split, 32 rows each)
    const int wn   = wid & 1;         // 0..1  (N split, 48 cols each)
    const int l15  = lane & 15;
    const int lq   = lane >> 4;

    // A staging geometry (2 chunks of 8 f32 per thread per k-tile)
    const int aid0  = tid;
    const int aid1  = NTHR + tid;
    const int arow0 = aid0 >> 3, ac0 = (aid0 & 7) * 16;   // byte col in 128-B bf16 row
    const int arow1 = aid1 >> 3, ac1 = (aid1 & 7) * 16;
    const int asw0  = ac0 ^ ((arow0 & 7) << 4);
    const int asw1  = ac1 ^ ((arow1 & 7) << 4);
    const float* ga0base = A + (size_t)(m0 + arow0) * D_SZ + (ac0 >> 1);
    const float* ga1base = A + (size_t)(m0 + arow1) * D_SZ + (ac1 >> 1);

    // ---- prologue: A(0) loads first, then B panel gload_lds (6 rounds)
    f32x4 x0 = *(const f32x4*)ga0base, x1 = *(const f32x4*)(ga0base + 4);
    f32x4 x2 = *(const f32x4*)ga1base, x3 = *(const f32x4*)(ga1base + 4);
    #pragma unroll
    for (int r2 = 0; r2 < 6; ++r2) {
        int p    = (r2 * NTHR + tid) * 16;          // linear LDS byte pos in Bs
        int kt   = p / BTILE;
        int rem  = p - kt * BTILE;
        int row  = rem >> 7;
        int kb   = rem & 127;
        int clog = kb ^ ((row & 7) << 4);           // involution within 128-B row
        const uint16_t* g = Wt + (n0 + row) * 256 + kt * BK + (clog >> 1);
        __builtin_amdgcn_global_load_lds(
            (const __attribute__((address_space(1))) uint32_t*)g,
            (__attribute__((address_space(3))) uint32_t*)(Bs + p), 16, 0, 0);
    }
    {   // pack A(0) -> As[0]  (waits only the 4 A loads: vmcnt(6))
        u32x4 v0 = { pk_bf16(x0.x,x0.y), pk_bf16(x0.z,x0.w), pk_bf16(x1.x,x1.y), pk_bf16(x1.z,x1.w) };
        u32x4 v1 = { pk_bf16(x2.x,x2.y), pk_bf16(x2.z,x2.w), pk_bf16(x3.x,x3.y), pk_bf16(x3.z,x3.w) };
        *(u32x4*)(As[0] + arow0 * 128 + asw0) = v0;
        *(u32x4*)(As[0] + arow1 * 128 + asw1) = v1;
    }
    __syncthreads();   // one-time full drain (B panel + A(0) writes)

    f32x4 acc[2][3];
    #pragma unroll
    for (int mf = 0; mf < 2; ++mf)
        #pragma unroll
        for (int nf = 0; nf < 3; ++nf)
            acc[mf][nf] = (f32x4){0.f, 0.f, 0.f, 0.f};

    const int brow0 = wn * 48 + l15;
    #pragma unroll
    for (int kt = 0; kt < KT; ++kt) {
        const char* AsC = As[kt & 1];
        // ---- issue A(t+1) loads (latency hides under MFMA below)
        f32x4 xn0, xn1, xn2, xn3;
        if (kt < KT - 1) {
            const float* g0 = ga0base + (kt + 1) * BK;
            const float* g1 = ga1base + (kt + 1) * BK;
            xn0 = *(const f32x4*)g0; xn1 = *(const f32x4*)(g0 + 4);
            xn2 = *(const f32x4*)g1; xn3 = *(const f32x4*)(g1 + 4);
        }
        // ---- compute tile kt: 2 kk x (2 A-frags, 3 B-frags) -> 12 MFMA
        #pragma unroll
        for (int kk = 0; kk < 2; ++kk) {
            const int kb = kk * 64 + lq * 16;
            bf16x8 af[2], bfr[3];
            #pragma unroll
            for (int mf = 0; mf < 2; ++mf) {
                int row = wm * 32 + mf * 16 + l15;
                af[mf] = *(const bf16x8*)(AsC + row * 128 + (kb ^ ((row & 7) << 4)));
            }
            #pragma unroll
            for (int nf = 0; nf < 3; ++nf) {
                int row = brow0 + nf * 16;
                bfr[nf] = *(const bf16x8*)(Bs + kt * BTILE + row * 128 + (kb ^ ((row & 7) << 4)));
            }
            #pragma unroll
            for (int mf = 0; mf < 2; ++mf)
                #pragma unroll
                for (int nf = 0; nf < 3; ++nf)
                    acc[mf][nf] = __builtin_amdgcn_mfma_f32_16x16x32_bf16(
                        af[mf], bfr[nf], acc[mf][nf], 0, 0, 0);
        }
        // ---- pack+write A(t+1), then lgkm-only barrier (no vmcnt drain:
        // only private reg loads are outstanding; buffers alternate -> race-free)
        if (kt < KT - 1) {
            char* AsN = As[(kt + 1) & 1];
            u32x4 v0 = { pk_bf16(xn0.x,xn0.y), pk_bf16(xn0.z,xn0.w), pk_bf16(xn1.x,xn1.y), pk_bf16(xn1.z,xn1.w) };
            u32x4 v1 = { pk_bf16(xn2.x,xn2.y), pk_bf16(xn2.z,xn2.w), pk_bf16(xn3.x,xn3.y), pk_bf16(xn3.z,xn3.w) };
            *(u32x4*)(AsN + arow0 * 128 + asw0) = v0;
            *(u32x4*)(AsN + arow1 * 128 + asw1) = v1;
            asm volatile("s_waitcnt lgkmcnt(0)" ::: "memory");
            __builtin_amdgcn_s_barrier();
        }
    }

    // --- fused epilogue: c = sig(i)*tanh(g), h = sig(o)*tanh(o) = (1-e^-o)/(1+e^-2o)
    const float L2E = 1.44269504088896340736f;
    const int jj = (nb * 2 + wn) * 16 + l15;              // hidden index 0..255
    const int bb = n0 + wn * 48 + l15;
    const float bi = biasp[bb];
    const float bg = biasp[bb + 16];
    const float bo = biasp[bb + 32];
    float* __restrict__ eh = out + EDGE_H_OFF;
    float* __restrict__ ec = out + EDGE_C_OFF;
    #pragma unroll
    for (int mf = 0; mf < 2; ++mf) {
        const int mbase = m0 + wm * 32 + mf * 16 + lq * 4;
        #pragma unroll
        for (int r = 0; r < 4; ++r) {
            const size_t m = (size_t)(mbase + r);
            float pi = acc[mf][0][r] + bi;
            float pg = acc[mf][1][r] + bg;
            float po = acc[mf][2][r] + bo;
            float ei = __builtin_amdgcn_exp2f(-L2E * pi);          // e^-i
            float eg = __builtin_amdgcn_exp2f(-2.f * L2E * pg);    // e^-2g
            float eo = __builtin_amdgcn_exp2f(-L2E * po);          // e^-o
            float c  = (1.f - eg) * __builtin_amdgcn_rcpf((1.f + ei) * (1.f + eg));
            float h  = (1.f - eo) * __builtin_amdgcn_rcpf(1.f + eo * eo);
            eh[m * H_SZ + jj] = h;
            ec[m * H_SZ + jj] = c;
        }
    }
}

// node_{h,c}[b,t,:] = mean over k of edge_{h,c}[b, prev[t,k], :]
// one wave per (b,t) pair; float4 per lane covers the 256-wide row.
__global__ void node_mean_kernel(const int* __restrict__ prev,
                                 const float* __restrict__ outr,
                                 float* __restrict__ out) {
    int gid  = blockIdx.x * 4 + (threadIdx.x >> 6);       // 0..16383
    int lane = threadIdx.x & 63;
    int b = gid >> 11;
    int t = gid & 2047;
    const float* eh = outr + EDGE_H_OFF + (size_t)b * E_SZ * H_SZ;
    const float* ec = outr + EDGE_C_OFF + (size_t)b * E_SZ * H_SZ;
    i32x4 e4 = *(const i32x4*)(prev + t * 4);
    f32x4 hs = (f32x4){0.f,0.f,0.f,0.f};
    f32x4 cs = (f32x4){0.f,0.f,0.f,0.f};
    #pragma unroll
    for (int k = 0; k < 4; ++k) {
        size_t off = (size_t)e4[k] * H_SZ + lane * 4;
        hs += *(const f32x4*)(eh + off);
        cs += *(const f32x4*)(ec + off);
    }
    hs *= 0.25f; cs *= 0.25f;
    size_t o = (size_t)(b * T_SZ + t) * H_SZ + lane * 4;
    *(f32x4*)(out + NODE_H_OFF + o) = hs;
    *(f32x4*)(out + NODE_C_OFF + o) = cs;
}

extern "C" void kernel_launch(void* const* d_in, const int* in_sizes, int n_in,
                              void* d_out, int out_size, void* d_ws, size_t ws_size,
                              hipStream_t stream) {
    const float* edge_input = (const float*)d_in[0];
    const float* weight_ih  = (const float*)d_in[1];
    // d_in[2] = weight_hh: mathematically dead (node_h read before write => 0)
    const float* bias       = (const float*)d_in[3];
    const int*   prev_idx   = (const int*)d_in[4];
    float* out = (float*)d_out;

    uint16_t* Wt    = (uint16_t*)d_ws;                    // 768*256*2 = 384 KiB
    float*    biasp = (float*)((char*)d_ws + NP * 256 * 2);

    wcvt_kernel<<<(256 * 768 + 255) / 256, 256, 0, stream>>>(weight_ih, bias, Wt, biasp);
    gemm_act_kernel<<<NWG, NTHR, 0, stream>>>(edge_input, Wt, biasp, out);
    node_mean_kernel<<<(B_SZ * T_SZ) / 4, 256, 0, stream>>>(prev_idx, out, out);
}